// Round 5
// baseline (150.179 us; speedup 1.0000x reference)
//
#include <hip/hip_runtime.h>
#include <hip/hip_bf16.h>

// Problem constants (fixed by the reference file)
constexpr int B_   = 8;
constexpr int C_   = 3;
constexpr int HW_  = 1024 * 1024;         // H*W = 2^20
constexpr int NPIX = B_ * HW_;            // 8,388,608 pixels = 2^23
constexpr int NV   = NPIX / 4;            // float4 groups = 2^21
constexpr int HWV  = HW_ / 4;             // 2^18 vec groups per image
constexpr int BLOCK = 256;
constexpr int GRID  = 2048;               // 8 blocks/CU * 256 CUs, all co-resident
constexpr int THREADS = GRID * BLOCK;     // 2^19

// ln(1e-8)
#define LOGMIN (-18.420680743952367f)
// 1/(B*H*W) = 2^-23 (exact in fp32)
#define INV_DENOM (1.1920928955078125e-07f)

__global__ __launch_bounds__(BLOCK) void ce_fused_kernel(
    const float* __restrict__ x,        // [B][C][H][W]
    const int*   __restrict__ y,        // [B][H][W]
    const float* __restrict__ weight,   // [C]
    const float* __restrict__ mask,     // [B][H][W]
    float*       __restrict__ partials, // [GRID] in d_ws
    unsigned*    __restrict__ counter,  // 1 uint in d_ws (memset to 0 per call)
    float*       __restrict__ out)
{
    const float w0 = weight[0];
    const float w1 = weight[1];
    const float w2 = weight[2];

    float acc = 0.0f;   // accumulates w[y] * logp_y * mask (positive-sign form)

    const int tid = blockIdx.x * BLOCK + threadIdx.x;

    for (int pv = tid; pv < NV; pv += THREADS) {
        const int b  = pv >> 18;            // pv / HWV
        const int sv = pv & (HWV - 1);      // pv % HWV
        const size_t base = (size_t)b * (size_t)(C_ * HW_) + (size_t)sv * 4;

        const float4 xa = *reinterpret_cast<const float4*>(x + base);
        const float4 xb = *reinterpret_cast<const float4*>(x + base + HW_);
        const float4 xc = *reinterpret_cast<const float4*>(x + base + 2 * (size_t)HW_);
        const int4   yv = *reinterpret_cast<const int4*>(y + (size_t)pv * 4);
        const float4 mv = *reinterpret_cast<const float4*>(mask + (size_t)pv * 4);

        const float a0[4] = {xa.x, xa.y, xa.z, xa.w};
        const float a1[4] = {xb.x, xb.y, xb.z, xb.w};
        const float a2[4] = {xc.x, xc.y, xc.z, xc.w};
        const int   yy[4] = {yv.x, yv.y, yv.z, yv.w};
        const float mm[4] = {mv.x, mv.y, mv.z, mv.w};

        #pragma unroll
        for (int j = 0; j < 4; ++j) {
            const float v0 = a0[j], v1 = a1[j], v2 = a2[j];
            const float m   = fmaxf(fmaxf(v0, v1), v2);
            const float t   = __expf(v0 - m) + __expf(v1 - m) + __expf(v2 - m);
            const float lse = m + __logf(t);
            const int   c   = yy[j];
            const float ay  = (c == 0) ? v0 : ((c == 1) ? v1 : v2);
            const float wy  = (c == 0) ? w0 : ((c == 1) ? w1 : w2);
            const float lp  = fmaxf(ay - lse, LOGMIN);
            acc = fmaf(wy * lp, mm[j], acc);
        }
    }

    // ---- wave (64-lane) reduction ----
    #pragma unroll
    for (int off = 32; off > 0; off >>= 1)
        acc += __shfl_down(acc, off, 64);

    __shared__ float    wsum[BLOCK / 64];
    __shared__ unsigned s_old;
    const int lane = threadIdx.x & 63;
    const int wid  = threadIdx.x >> 6;
    if (lane == 0) wsum[wid] = acc;
    __syncthreads();

    if (threadIdx.x == 0) {
        const float bs = wsum[0] + wsum[1] + wsum[2] + wsum[3];
        // release the partial, then bump the counter (agent scope: cross-XCD safe)
        __hip_atomic_store(&partials[blockIdx.x], bs,
                           __ATOMIC_RELEASE, __HIP_MEMORY_SCOPE_AGENT);
        s_old = __hip_atomic_fetch_add(counter, 1u,
                                       __ATOMIC_ACQ_REL, __HIP_MEMORY_SCOPE_AGENT);
    }
    __syncthreads();

    if (s_old == GRID - 1) {
        // last block to finish: reduce all partials and write the result
        float s = 0.0f;
        for (int i = threadIdx.x; i < GRID; i += BLOCK)
            s += __hip_atomic_load(&partials[i],
                                   __ATOMIC_ACQUIRE, __HIP_MEMORY_SCOPE_AGENT);

        #pragma unroll
        for (int off = 32; off > 0; off >>= 1)
            s += __shfl_down(s, off, 64);

        __syncthreads();                 // wsum reuse barrier
        if (lane == 0) wsum[wid] = s;
        __syncthreads();

        if (threadIdx.x == 0) {
            const float total = wsum[0] + wsum[1] + wsum[2] + wsum[3];
            out[0] = total * (-INV_DENOM);   // ce = -w*lp*mask, then / denom
        }
    }
}

extern "C" void kernel_launch(void* const* d_in, const int* in_sizes, int n_in,
                              void* d_out, int out_size, void* d_ws, size_t ws_size,
                              hipStream_t stream) {
    const float* x      = (const float*)d_in[0];
    const int*   y      = (const int*)d_in[1];
    const float* weight = (const float*)d_in[2];
    const float* mask   = (const float*)d_in[3];
    float* out = (float*)d_out;

    float*    partials = (float*)d_ws;                          // 8 KB
    unsigned* counter  = (unsigned*)((char*)d_ws + GRID * 4);   // own cache line region

    hipMemsetAsync(counter, 0, sizeof(unsigned), stream);       // capturable node
    ce_fused_kernel<<<GRID, BLOCK, 0, stream>>>(x, y, weight, mask,
                                                partials, counter, out);
}

// Round 6
// 32.977 us; speedup vs baseline: 4.5541x; 4.5541x over previous
//
#include <hip/hip_runtime.h>
#include <hip/hip_bf16.h>

// Problem constants (fixed by the reference file)
constexpr int B_   = 8;
constexpr int C_   = 3;
constexpr int HW_  = 1024 * 1024;         // H*W = 2^20
constexpr int NPIX = B_ * HW_;            // 8,388,608 pixels = 2^23
constexpr int NV   = NPIX / 4;            // float4 groups = 2^21
constexpr int HWV  = HW_ / 4;             // 2^18 vec groups per image
constexpr int BLOCK = 256;
constexpr int GRID  = 2048;               // 8 blocks/CU * 256 CUs, all co-resident

// ln(1e-8)
#define LOGMIN (-18.420680743952367f)
// 1/(B*H*W) = 2^-23 (exact in fp32)
#define INV_DENOM (1.1920928955078125e-07f)

__global__ __launch_bounds__(BLOCK) void ce_partial_kernel(
    const float* __restrict__ x,        // [B][C][H][W]
    const int*   __restrict__ y,        // [B][H][W]
    const float* __restrict__ weight,   // [C]
    const float* __restrict__ mask,     // [B][H][W]
    float* __restrict__ partials)       // [GRID]
{
    const float w0 = weight[0];
    const float w1 = weight[1];
    const float w2 = weight[2];

    float acc = 0.0f;   // accumulates w[y] * logp_y * mask (positive-sign form)

    const int tid    = blockIdx.x * BLOCK + threadIdx.x;
    const int stride = GRID * BLOCK;

    for (int pv = tid; pv < NV; pv += stride) {
        const int b  = pv >> 18;            // pv / HWV
        const int sv = pv & (HWV - 1);      // pv % HWV
        const size_t base = (size_t)b * (size_t)(C_ * HW_) + (size_t)sv * 4;

        const float4 xa = *reinterpret_cast<const float4*>(x + base);
        const float4 xb = *reinterpret_cast<const float4*>(x + base + HW_);
        const float4 xc = *reinterpret_cast<const float4*>(x + base + 2 * (size_t)HW_);
        const int4   yv = *reinterpret_cast<const int4*>(y + (size_t)pv * 4);
        const float4 mv = *reinterpret_cast<const float4*>(mask + (size_t)pv * 4);

        const float a0[4] = {xa.x, xa.y, xa.z, xa.w};
        const float a1[4] = {xb.x, xb.y, xb.z, xb.w};
        const float a2[4] = {xc.x, xc.y, xc.z, xc.w};
        const int   yy[4] = {yv.x, yv.y, yv.z, yv.w};
        const float mm[4] = {mv.x, mv.y, mv.z, mv.w};

        #pragma unroll
        for (int j = 0; j < 4; ++j) {
            const float v0 = a0[j], v1 = a1[j], v2 = a2[j];
            const float m   = fmaxf(fmaxf(v0, v1), v2);
            const float t   = __expf(v0 - m) + __expf(v1 - m) + __expf(v2 - m);
            const float lse = m + __logf(t);
            const int   c   = yy[j];
            const float ay  = (c == 0) ? v0 : ((c == 1) ? v1 : v2);
            const float wy  = (c == 0) ? w0 : ((c == 1) ? w1 : w2);
            const float lp  = fmaxf(ay - lse, LOGMIN);
            acc = fmaf(wy * lp, mm[j], acc);
        }
    }

    // ---- wave (64-lane) reduction ----
    #pragma unroll
    for (int off = 32; off > 0; off >>= 1)
        acc += __shfl_down(acc, off, 64);

    __shared__ float wsum[BLOCK / 64];
    const int lane = threadIdx.x & 63;
    const int wid  = threadIdx.x >> 6;
    if (lane == 0) wsum[wid] = acc;
    __syncthreads();

    if (threadIdx.x == 0)
        partials[blockIdx.x] = wsum[0] + wsum[1] + wsum[2] + wsum[3];
}

// single-wave final reduction: 2048 floats = 8 float4 per lane
__global__ __launch_bounds__(64) void reduce_kernel(
    const float* __restrict__ partials, float* __restrict__ out)
{
    float s = 0.0f;
    #pragma unroll
    for (int k = 0; k < GRID / (64 * 4); ++k) {
        const float4 v = *reinterpret_cast<const float4*>(
            partials + (size_t)(k * 64 + threadIdx.x) * 4);
        s += (v.x + v.y) + (v.z + v.w);
    }

    #pragma unroll
    for (int off = 32; off > 0; off >>= 1)
        s += __shfl_down(s, off, 64);

    if (threadIdx.x == 0)
        out[0] = s * (-INV_DENOM);   // ce = -w*lp*mask, then / denom
}

extern "C" void kernel_launch(void* const* d_in, const int* in_sizes, int n_in,
                              void* d_out, int out_size, void* d_ws, size_t ws_size,
                              hipStream_t stream) {
    const float* x      = (const float*)d_in[0];
    const int*   y      = (const int*)d_in[1];
    const float* weight = (const float*)d_in[2];
    const float* mask   = (const float*)d_in[3];
    float* out      = (float*)d_out;
    float* partials = (float*)d_ws;     // GRID floats = 8 KB << ws_size

    ce_partial_kernel<<<GRID, BLOCK, 0, stream>>>(x, y, weight, mask, partials);
    reduce_kernel<<<1, 64, 0, stream>>>(partials, out);
}

// Round 7
// 32.895 us; speedup vs baseline: 4.5654x; 1.0025x over previous
//
#include <hip/hip_runtime.h>
#include <hip/hip_bf16.h>

// Problem constants (fixed by the reference file)
constexpr int B_   = 8;
constexpr int C_   = 3;
constexpr int HW_  = 1024 * 1024;         // H*W = 2^20
constexpr int NPIX = B_ * HW_;            // 8,388,608 pixels = 2^23
constexpr int NV   = NPIX / 4;            // float4 groups = 2^21
constexpr int HWV  = HW_ / 4;             // 2^18 vec groups per image
constexpr int BLOCK = 256;
constexpr int GRID  = NV / BLOCK;         // 8192 blocks, 1 vec-group per thread

// ln(1e-8)
#define LOGMIN (-18.420680743952367f)
// 1/(B*H*W) = 2^-23 (exact in fp32)
#define INV_DENOM (1.1920928955078125e-07f)

__global__ __launch_bounds__(BLOCK) void ce_partial_kernel(
    const float* __restrict__ x,        // [B][C][H][W]
    const int*   __restrict__ y,        // [B][H][W]
    const float* __restrict__ weight,   // [C]
    const float* __restrict__ mask,     // [B][H][W]
    float* __restrict__ partials)       // [GRID]
{
    const float w0 = weight[0];
    const float w1 = weight[1];
    const float w2 = weight[2];

    // exactly one vec-group (4 pixels) per thread: one load batch, one compute
    const int pv = blockIdx.x * BLOCK + threadIdx.x;   // < 2^21
    const int b  = pv >> 18;            // pv / HWV
    const int sv = pv & (HWV - 1);      // pv % HWV
    const size_t base = (size_t)b * (size_t)(C_ * HW_) + (size_t)sv * 4;

    const float4 xa = *reinterpret_cast<const float4*>(x + base);
    const float4 xb = *reinterpret_cast<const float4*>(x + base + HW_);
    const float4 xc = *reinterpret_cast<const float4*>(x + base + 2 * (size_t)HW_);
    const int4   yv = *reinterpret_cast<const int4*>(y + (size_t)pv * 4);
    const float4 mv = *reinterpret_cast<const float4*>(mask + (size_t)pv * 4);

    const float a0[4] = {xa.x, xa.y, xa.z, xa.w};
    const float a1[4] = {xb.x, xb.y, xb.z, xb.w};
    const float a2[4] = {xc.x, xc.y, xc.z, xc.w};
    const int   yy[4] = {yv.x, yv.y, yv.z, yv.w};
    const float mm[4] = {mv.x, mv.y, mv.z, mv.w};

    float acc = 0.0f;   // accumulates w[y] * logp_y * mask (positive-sign form)
    #pragma unroll
    for (int j = 0; j < 4; ++j) {
        const float v0 = a0[j], v1 = a1[j], v2 = a2[j];
        const float m   = fmaxf(fmaxf(v0, v1), v2);
        const float t   = __expf(v0 - m) + __expf(v1 - m) + __expf(v2 - m);
        const float lse = m + __logf(t);
        const int   c   = yy[j];
        const float ay  = (c == 0) ? v0 : ((c == 1) ? v1 : v2);
        const float wy  = (c == 0) ? w0 : ((c == 1) ? w1 : w2);
        const float lp  = fmaxf(ay - lse, LOGMIN);
        acc = fmaf(wy * lp, mm[j], acc);
    }

    // ---- wave (64-lane) reduction ----
    #pragma unroll
    for (int off = 32; off > 0; off >>= 1)
        acc += __shfl_down(acc, off, 64);

    __shared__ float wsum[BLOCK / 64];
    const int lane = threadIdx.x & 63;
    const int wid  = threadIdx.x >> 6;
    if (lane == 0) wsum[wid] = acc;
    __syncthreads();

    if (threadIdx.x == 0)
        partials[blockIdx.x] = wsum[0] + wsum[1] + wsum[2] + wsum[3];
}

// final reduction: 8192 floats = 32 KB, one block of 256 threads
__global__ __launch_bounds__(256) void reduce_kernel(
    const float* __restrict__ partials, float* __restrict__ out)
{
    float s = 0.0f;
    #pragma unroll
    for (int k = 0; k < GRID / (256 * 4); ++k) {   // 8 float4 per thread
        const float4 v = *reinterpret_cast<const float4*>(
            partials + (size_t)(k * 256 + threadIdx.x) * 4);
        s += (v.x + v.y) + (v.z + v.w);
    }

    #pragma unroll
    for (int off = 32; off > 0; off >>= 1)
        s += __shfl_down(s, off, 64);

    __shared__ float wsum[4];
    const int lane = threadIdx.x & 63;
    const int wid  = threadIdx.x >> 6;
    if (lane == 0) wsum[wid] = s;
    __syncthreads();

    if (threadIdx.x == 0) {
        const float total = wsum[0] + wsum[1] + wsum[2] + wsum[3];
        out[0] = total * (-INV_DENOM);   // ce = -w*lp*mask, then / denom
    }
}

extern "C" void kernel_launch(void* const* d_in, const int* in_sizes, int n_in,
                              void* d_out, int out_size, void* d_ws, size_t ws_size,
                              hipStream_t stream) {
    const float* x      = (const float*)d_in[0];
    const int*   y      = (const int*)d_in[1];
    const float* weight = (const float*)d_in[2];
    const float* mask   = (const float*)d_in[3];
    float* out      = (float*)d_out;
    float* partials = (float*)d_ws;     // GRID floats = 32 KB << ws_size

    ce_partial_kernel<<<GRID, BLOCK, 0, stream>>>(x, y, weight, mask, partials);
    reduce_kernel<<<1, 256, 0, stream>>>(partials, out);
}